// Round 1
// baseline (1150.304 us; speedup 1.0000x reference)
//
#include <hip/hip_runtime.h>

#define BROWS 65536
#define DDIM  64

// 8 rows per wave, 8 lanes per row, 8 elements per lane.
// Element j of a row maps to lane (j & 7) within the row's lane-group,
// register slot ei = j >> 3  (j = ei*8 + sub).

__global__ __launch_bounds__(256) void esh_kernel(
    const float* __restrict__ x0,
    const float* __restrict__ u0,
    const float* __restrict__ prec,
    const float* __restrict__ epsp,
    const int*   __restrict__ nstepsp,
    float* __restrict__ out)
{
    const int tid  = threadIdx.x;
    const int wv   = tid >> 6;        // wave in block: 0..3
    const int lane = tid & 63;
    const int sub  = lane & 7;        // lane-in-row
    const int rg   = lane >> 3;       // row-group within wave: 0..7
    const int gw   = blockIdx.x * 4 + wv;   // global wave id: 0..8191
    const int row  = (gw << 3) + rg;        // 0..65535

    const float eps     = epsp[0];
    const int   n_steps = nstepsp[0];
    const float e       = 0.5f * eps;           // substep uses eps/2
    const float einvd   = e * (1.0f / 64.0f);   // e / d

    const size_t XU = (size_t)(n_steps + 1) * BROWS * DDIM; // traj_u offset
    const size_t RO = 2 * XU;                               // traj_r offset

    float x[8], u[8], p[8];
    {
        const float* xi = x0 + (size_t)row * DDIM;
        const float* ui = u0 + (size_t)row * DDIM;
#pragma unroll
        for (int ei = 0; ei < 8; ++ei) {
            int j = ei * 8 + sub;
            x[ei] = xi[j];
            u[ei] = ui[j];
            p[ei] = prec[j];
        }
    }
    float r = 0.0f;

    // Per-wave private LDS transpose tiles; row stride 68 (+4 pad) keeps
    // ds_write bank aliasing <= 2-way (free).
    __shared__ __align__(16) float lds[4][2][8 * 68];
    float* lx = &lds[wv][0][0];
    float* lu = &lds[wv][1][0];

    auto store_step = [&](int t) {
#pragma unroll
        for (int ei = 0; ei < 8; ++ei) {
            lx[rg * 68 + ei * 8 + sub] = x[ei];
            lu[rg * 68 + ei * 8 + sub] = u[ei];
        }
        // Read back in output (row-major, dense) order: 2 x float4 per lane.
        const int f0 = lane * 4;        // flat float index 0..255
        const int r0 = f0 >> 6, c0 = f0 & 63;
        const int f1 = 256 + lane * 4;  // 256..511
        const int r1 = f1 >> 6, c1 = f1 & 63;
        float4 vx0 = *(const float4*)&lx[r0 * 68 + c0];
        float4 vx1 = *(const float4*)&lx[r1 * 68 + c1];
        float4 vu0 = *(const float4*)&lu[r0 * 68 + c0];
        float4 vu1 = *(const float4*)&lu[r1 * 68 + c1];

        float* ox = out + (size_t)t * (BROWS * DDIM) + (size_t)gw * (8 * DDIM);
        float* ou = ox + XU;
        ((float4*)ox)[lane]      = vx0;
        ((float4*)ox)[64 + lane] = vx1;
        ((float4*)ou)[lane]      = vu0;
        ((float4*)ou)[64 + lane] = vu1;
        if (sub == 0) out[RO + (size_t)t * BROWS + row] = r;
    };

    auto substep = [&]() {
        float g[8];
        float gn2 = 0.0f, udg = 0.0f;
#pragma unroll
        for (int ei = 0; ei < 8; ++ei) {
            g[ei] = p[ei] * x[ei];
            gn2 = fmaf(g[ei], g[ei], gn2);
            udg = fmaf(u[ei], g[ei], udg);
        }
#pragma unroll
        for (int m = 1; m < 8; m <<= 1) {
            gn2 += __shfl_xor(gn2, m, 64);
            udg += __shfl_xor(udg, m, 64);
        }
        float gn0     = fmaxf(sqrtf(gn2), 1e-10f);
        float g_norm  = fminf(gn0, 10.0f);       // MAX_GRAD_NORM
        float inv_gn0 = 1.0f / gn0;
        float ud      = -udg * inv_gn0;          // u_dot_e
        float t1      = __expf(-einvd * g_norm); // exp(-e*g_norm/d)
        float ex2     = t1 * t1;                 // exp(-2*e*g_norm/d)
        float A2      = (ud - 1.0f) * ex2;
        float A       = 1.0f + ud + A2;
        float Bc      = 2.0f * t1;
        bool  cond    = ud > -0.999f;
        // u_new = cond ? Bc*u + grad_e*(Bc*ud - A) : grad_e, grad_e = g*inv_gn0
        float c1 = cond ? Bc : 0.0f;
        float c2 = (cond ? (Bc * ud - A) : 1.0f) * inv_gn0;
        float n2 = 0.0f;
#pragma unroll
        for (int ei = 0; ei < 8; ++ei) {
            float un = fmaf(c1, u[ei], c2 * g[ei]);
            u[ei] = un;
            n2 = fmaf(un, un, n2);
        }
#pragma unroll
        for (int m = 1; m < 8; m <<= 1) n2 += __shfl_xor(n2, m, 64);
        float invn = 1.0f / fmaxf(sqrtf(n2), 1e-10f);
#pragma unroll
        for (int ei = 0; ei < 8; ++ei) u[ei] *= invn;
        float Z  = 1.0f + ud - A2;
        float dr = cond ? (einvd * g_norm + __logf(0.5f * fmaxf(Z, 1e-10f)))
                        : (-einvd * g_norm);
        r += dr;
    };

    store_step(0);
    for (int t = 0; t < n_steps; ++t) {
        substep();
#pragma unroll
        for (int ei = 0; ei < 8; ++ei) x[ei] = fmaf(eps, u[ei], x[ei]);
        substep();
        store_step(t + 1);
    }
}

extern "C" void kernel_launch(void* const* d_in, const int* in_sizes, int n_in,
                              void* d_out, int out_size, void* d_ws, size_t ws_size,
                              hipStream_t stream) {
    const float* x0    = (const float*)d_in[0];
    const float* u0    = (const float*)d_in[1];
    const float* prec  = (const float*)d_in[2];
    const float* epsp  = (const float*)d_in[3];
    const int*   nst   = (const int*)d_in[4];
    float* out = (float*)d_out;

    const int waves  = BROWS / 8;       // 8192
    const int blocks = waves / 4;       // 2048
    esh_kernel<<<blocks, 256, 0, stream>>>(x0, u0, prec, epsp, nst, out);
}